// Round 6
// baseline (2151.409 us; speedup 1.0000x reference)
//
#include <hip/hip_runtime.h>

// ---------------------------------------------------------------------------
// LSTM autoencoder w/ attention, MI355X fp16-MFMA implementation.
// S=128, B=256, IN=H=OUT=1024.  All GEMMs plain fp16 inputs, fp32 accumulate.
// R7: k_step inner loop moved to 32x32x16 MFMA (R5-verified fragment/C
//     layouts) with ALL staging via global_load_lds in the R1/R6-proven
//     4-buffer depth-2 counted-vmcnt schedule.  8 waves = 4 K-quarter
//     groups x 2 m-halves; per wave-iter: 6 ds_read_b128 -> 4 MFMA
//     (vs R6's 10 -> 8 at 16x16), cutting the per-CU LDS-pipe time from
//     ~6.4us to ~3.8us per step.  fp32 K-partials merge via the verified
//     EX exchange; cell update unchanged.
// ---------------------------------------------------------------------------

typedef _Float16 half8 __attribute__((ext_vector_type(8)));
typedef float f32x4 __attribute__((ext_vector_type(4)));
typedef float f32x16 __attribute__((ext_vector_type(16)));

#define S_  128
#define B_  256
#define HDIM 1024
#define BH  262144          // B*H

// async global -> LDS, 16B per lane, wave-uniform LDS base
__device__ __forceinline__ void g2l16(void* lds_base, const void* g) {
  __builtin_amdgcn_global_load_lds(
      (const __attribute__((address_space(1))) void*)g,
      (__attribute__((address_space(3))) void*)lds_base, 16, 0, 0);
}

__device__ __forceinline__ float sigmoidf_(float x) {
  return 1.f / (1.f + __expf(-x));
}
__device__ __forceinline__ float tanhf_(float x) {
  float e = __expf(-2.f * fabsf(x));
  float t = (1.f - e) / (1.f + e);
  return x < 0.f ? -t : t;
}

// --------------------------- converters ------------------------------------
__global__ __launch_bounds__(256) void k_cvt(const float* __restrict__ src,
                                             _Float16* __restrict__ dst) {
  size_t i = ((size_t)blockIdx.x * 256 + threadIdx.x) * 8;
  float4 u = *(const float4*)(src + i);
  float4 v = *(const float4*)(src + i + 4);
  half8 h;
  h[0] = u.x; h[1] = u.y; h[2] = u.z; h[3] = u.w;
  h[4] = v.x; h[5] = v.y; h[6] = v.z; h[7] = v.w;
  *(half8*)(dst + i) = h;
}

// Wcat[r][k] = k<1024 ? W_ih[r][k] : W_hh[r][k-1024]   (fp16, [4096][2048])
__global__ __launch_bounds__(256) void k_wcat(const float* __restrict__ Wih,
                                              const float* __restrict__ Whh,
                                              _Float16* __restrict__ Wc) {
  size_t i = ((size_t)blockIdx.x * 256 + threadIdx.x) * 8;
  int r = (int)(i >> 11), k = (int)(i & 2047);
  const float* src = (k < 1024) ? (Wih + (size_t)r * 1024 + k)
                                : (Whh + (size_t)r * 1024 + (k - 1024));
  float4 u = *(const float4*)(src);
  float4 v = *(const float4*)(src + 4);
  half8 h;
  h[0] = u.x; h[1] = u.y; h[2] = u.z; h[3] = u.w;
  h[4] = v.x; h[5] = v.y; h[6] = v.z; h[7] = v.w;
  *(half8*)(Wc + i) = h;
}

// cbuf = c0 ; hs[0] = fp16(h0) ; bias = b_ih + b_hh
__global__ __launch_bounds__(256) void k_init(const float* __restrict__ h0,
                                              const float* __restrict__ c0,
                                              const float* __restrict__ bih,
                                              const float* __restrict__ bhh,
                                              _Float16* __restrict__ hs0,
                                              float* __restrict__ cbuf,
                                              float* __restrict__ bias) {
  int i = blockIdx.x * 256 + threadIdx.x;   // 262144 total
  cbuf[i] = c0[i];
  hs0[i] = (_Float16)h0[i];
  if (i < 4096) bias[i] = bih[i] + bhh[i];
}

// row softmax of attnW [128][128] -> fp16 Ah + fp16 residual Ar
__global__ __launch_bounds__(64) void k_softmax(const float* __restrict__ W,
                                                _Float16* __restrict__ Ah,
                                                _Float16* __restrict__ Ar) {
  int r = blockIdx.x, lane = threadIdx.x;
  float v0 = W[r * 128 + lane], v1 = W[r * 128 + 64 + lane];
  float m = fmaxf(v0, v1);
  for (int off = 32; off; off >>= 1) m = fmaxf(m, __shfl_xor(m, off));
  float e0 = __expf(v0 - m), e1 = __expf(v1 - m);
  float s = e0 + e1;
  for (int off = 32; off; off >>= 1) s += __shfl_xor(s, off);
  float inv = 1.f / s;
  float a0 = e0 * inv, a1 = e1 * inv;
  _Float16 h0 = (_Float16)a0, h1 = (_Float16)a1;
  Ah[r * 128 + lane] = h0;
  Ah[r * 128 + 64 + lane] = h1;
  Ar[r * 128 + lane] = (_Float16)(a0 - (float)h0);
  Ar[r * 128 + 64 + lane] = (_Float16)(a1 - (float)h1);
}

// --------------------------- fused LSTM step --------------------------------
// gates[B,4H] = [x_t | h_{t-1}] @ Wcat^T + bias, then cell, h -> hs[t+1].
// Block: 64 batch-rows x 16 H-cols x 4 gates (64 gate-rows).  Grid 256,
// 512 threads.  wid = kq*2 + mh: kq = K-quarter (512 wide), mh = m-half.
// Per group: BK=32, 4 x 8KB LDS buffers, depth-2 prefetch, counted vmcnt
// (8/4/0 - R6-identical discipline), one barrier per iter, 16 iters.
// Wave computes 32m x 64gr via 32x32x16 MFMA: per iter 6 ds_read_b128 ->
// 4 MFMA.  fp32 K-partials merge via EX exchange (R5-verified layouts).
__global__ __launch_bounds__(512) void k_step(const _Float16* __restrict__ Xh,
                                              const _Float16* __restrict__ Wc,
                                              const float* __restrict__ bias,
                                              _Float16* __restrict__ hs,
                                              float* __restrict__ cbuf,
                                              int t) {
  __shared__ char smem[131072];   // 4 groups x 4 bufs x 8KB; EX overlays after
  const int tid = threadIdx.x;
  const int lane = tid & 63;
  const int wid = tid >> 6;
  const int kq = wid >> 1;          // K-quarter 0..3
  const int mh = wid & 1;           // m-half within group
  const int tg = tid & 127;         // thread id within group
  const int l31 = lane & 31;
  const int lhi = lane >> 5;
  const int n_tile = blockIdx.x & 63;
  const int m_tile = blockIdx.x >> 6;
  const int n0 = n_tile * 16;
  const int m0 = m_tile * 64;

  const _Float16* Abase = (kq < 2) ? (Xh + (size_t)t * BH)
                                   : (hs + (size_t)t * BH);
  const int acolbase = (kq & 1) * 512;   // column base within x or h

  f32x16 acc0 = {0.f};   // gate-rows 0..31 (gates i,f)
  f32x16 acc1 = {0.f};   // gate-rows 32..63 (gates g,o)

  // ---- staging offsets: buffer = A[64 r][4 ch] (4KB) + B[64][4] (4KB) -----
  // slot s = q*128 + tg; q0,q1 -> A (s<256), q2,q3 -> B.  swizzle c^(r&3).
  int offA[2], offB[2];
  #pragma unroll
  for (int q = 0; q < 2; ++q) {
    int s = q * 128 + tg;
    int r = s >> 2, c = s & 3;
    int kc = c ^ (r & 3);
    offA[q] = (m0 + r) * 1024 + kc * 8;          // + acolbase + it*32
  }
  #pragma unroll
  for (int q = 0; q < 2; ++q) {
    int sb = q * 128 + tg;
    int r = sb >> 2, c = sb & 3;
    int kc = c ^ (r & 3);
    int row = (r >> 4) * 1024 + n0 + (r & 15);
    offB[q] = row * 2048 + kq * 512 + kc * 8;    // + it*32
  }

  char* gbase = smem + kq * 32768;
  auto stage = [&](int buf, int it) {
    char* base = gbase + buf * 8192;
    int ka = acolbase + it * 32;
    int kb = it * 32;
    g2l16(base +        mh * 1024, Abase + offA[0] + ka);
    g2l16(base + 2048 + mh * 1024, Abase + offA[1] + ka);
    g2l16(base + 4096 + mh * 1024, Wc + offB[0] + kb);
    g2l16(base + 6144 + mh * 1024, Wc + offB[1] + kb);
  };

  // ---- LDS read offsets (32x32x16 fragment layout, R5-verified) -----------
  // A: row = mh*32 + (lane&31), k16-step j, chunk = j*2 + (lane>>5).
  // B: row = f*32 + (lane&31) (gate-rows), same chunk rule.
  int aoff[2], boff[2][2];
  #pragma unroll
  for (int j = 0; j < 2; ++j) {
    int ra = mh * 32 + l31;
    int ca = j * 2 + lhi;
    aoff[j] = ra * 64 + ((ca ^ (ra & 3)) * 16);
    #pragma unroll
    for (int f = 0; f < 2; ++f) {
      int rb = f * 32 + l31;
      int cb = j * 2 + lhi;
      boff[f][j] = 4096 + rb * 64 + ((cb ^ (rb & 3)) * 16);
    }
  }

  stage(0, 0);
  stage(1, 1);

  #pragma unroll
  for (int it = 0; it < 16; ++it) {
    if (it < 14) stage((it + 2) & 3, it + 2);
    // drain this buffer's 4 loads; keep up to 8 (2 buffers) in flight.
    if (it < 14)       asm volatile("s_waitcnt vmcnt(8)" ::: "memory");
    else if (it == 14) asm volatile("s_waitcnt vmcnt(4)" ::: "memory");
    else               asm volatile("s_waitcnt vmcnt(0)" ::: "memory");
    __builtin_amdgcn_s_barrier();                   // buffer ready (all waves)
    const char* bb = gbase + (it & 3) * 8192;
    half8 a0 = *(const half8*)(bb + aoff[0]);
    half8 b0 = *(const half8*)(bb + boff[0][0]);
    half8 b1 = *(const half8*)(bb + boff[1][0]);
    acc0 = __builtin_amdgcn_mfma_f32_32x32x16_f16(a0, b0, acc0, 0, 0, 0);
    acc1 = __builtin_amdgcn_mfma_f32_32x32x16_f16(a0, b1, acc1, 0, 0, 0);
    half8 a1 = *(const half8*)(bb + aoff[1]);
    half8 b2 = *(const half8*)(bb + boff[0][1]);
    half8 b3 = *(const half8*)(bb + boff[1][1]);
    acc0 = __builtin_amdgcn_mfma_f32_32x32x16_f16(a1, b2, acc0, 0, 0, 0);
    acc1 = __builtin_amdgcn_mfma_f32_32x32x16_f16(a1, b3, acc1, 0, 0, 0);
  }

  __syncthreads();                    // all waves done with buffers

  // ---- EX exchange: EX[kq][64 m][66 pad] fp32 (overlays buffers) ----------
  // C layout (32x32, R5-verified): col = lane&31 (gate-row),
  // row = (e&3) + 8*(e>>2) + 4*(lane>>5).
  {
    float* EXg = (float*)smem + kq * 4224 + mh * 32 * 66;
    #pragma unroll
    for (int f = 0; f < 2; ++f) {
      const f32x16 a = f ? acc1 : acc0;
      int gr = f * 32 + l31;
      #pragma unroll
      for (int e = 0; e < 16; ++e) {
        int mr = (e & 3) + 8 * (e >> 2) + 4 * lhi;
        EXg[mr * 66 + gr] = a[e];
      }
    }
  }
  __syncthreads();

  // ---- cell update: 512 threads, 2 m-rows each ----------------------------
  {
    int nl = tid & 15;
    int mseg = tid >> 4;              // 0..31
    int n = n0 + nl;
    float bi = bias[n], bf2 = bias[1024 + n];
    float bg = bias[2048 + n], bo = bias[3072 + n];
    const float* EX = (const float*)smem;
    _Float16* hnext = hs + (size_t)(t + 1) * BH;
    #pragma unroll
    for (int rr = 0; rr < 2; ++rr) {
      int m = mseg * 2 + rr;
      const float* e = EX + m * 66;
      float gi = sigmoidf_(e[nl]      + e[4224 + nl]      + e[8448 + nl]      + e[12672 + nl]      + bi);
      float gf = sigmoidf_(e[16 + nl] + e[4224 + 16 + nl] + e[8448 + 16 + nl] + e[12672 + 16 + nl] + bf2);
      float gg = tanhf_   (e[32 + nl] + e[4224 + 32 + nl] + e[8448 + 32 + nl] + e[12672 + 32 + nl] + bg);
      float go = sigmoidf_(e[48 + nl] + e[4224 + 48 + nl] + e[8448 + 48 + nl] + e[12672 + 48 + nl] + bo);
      size_t idx = (size_t)(m0 + m) * 1024 + n;
      float c = gf * cbuf[idx] + gi * gg;
      cbuf[idx] = c;
      hnext[idx] = (_Float16)(go * tanhf_(c));
    }
  }
}

// --------------------------- attention mix (MFMA) ---------------------------
// att[x, n] = sum_y (Ah+Ar)[x,y] * hs[y+1, n].
__global__ __launch_bounds__(256) void k_attn(const _Float16* __restrict__ Ah,
                                              const _Float16* __restrict__ Ar,
                                              const _Float16* __restrict__ hs,
                                              _Float16* __restrict__ att) {
  __shared__ char smem[131072];
  const int tid = threadIdx.x;
  const int wave = tid >> 6;
  const int lane = tid & 63;
  const int n0 = blockIdx.x * 256;

  #pragma unroll
  for (int q = 0; q < 16; ++q) {
    int s = q * 256 + tid;
    char* dst = smem + (q * 4 + wave) * 1024;
    if (q < 8) {
      int r = s >> 4;
      int cl = (s & 15) ^ (r & 15);
      g2l16(dst, Ah + r * 128 + cl * 8);
    } else {
      int s2 = s - 2048;
      int r = s2 >> 4;
      int cl = (s2 & 15) ^ (r & 15);
      g2l16(dst, Ar + r * 128 + cl * 8);
    }
  }
  #pragma unroll
  for (int ch = 0; ch < 4; ++ch) {
    char* base = smem + 65536 + ch * 16384;
    #pragma unroll
    for (int q = 0; q < 4; ++q) {
      int s = q * 256 + tid;
      int y = s >> 5, cp = s & 31;
      int cl = cp ^ (((y >> 3) & 3) << 1);
      g2l16(base + (q * 4 + wave) * 1024,
            hs + (size_t)(1 + ch * 32 + y) * BH + n0 + cl * 8);
    }
  }

  f32x4 acc[8][4];
  #pragma unroll
  for (int m = 0; m < 8; ++m)
    #pragma unroll
    for (int nf = 0; nf < 4; ++nf) acc[m][nf] = (f32x4){0.f, 0.f, 0.f, 0.f};

  const int yg = lane >> 4;

  #pragma unroll
  for (int ch = 0; ch < 4; ++ch) {
    if (ch == 0)      asm volatile("s_waitcnt vmcnt(12)" ::: "memory");
    else if (ch == 1) asm volatile("s_waitcnt vmcnt(8)"  ::: "memory");
    else if (ch == 2) asm volatile("s_waitcnt vmcnt(4)"  ::: "memory");
    else              asm volatile("s_waitcnt vmcnt(0)"  ::: "memory");
    __builtin_amdgcn_s_barrier();

    const char* cb = smem + 65536 + ch * 16384;
    half8 b[4];
    #pragma unroll
    for (int nf = 0; nf < 4; ++nf) {
      int n = wave * 64 + nf * 16 + (lane & 15);
      const char* col = cb + (((n >> 3) ^ (yg << 1)) * 16) + (n & 7) * 2;
      #pragma unroll
      for (int j = 0; j < 8; ++j)
        b[nf][j] = *(const _Float16*)(col + (yg * 8 + j) * 512);
    }
    #pragma unroll
    for (int m = 0; m < 8; ++m) {
      int x = m * 16 + (lane & 15);
      int sw = ((ch * 4 + yg) ^ (x & 15)) * 16;
      half8 ah = *(const half8*)(smem + x * 256 + sw);
      half8 ar = *(const half8*)(smem + 32768 + x * 256 + sw);
      #pragma unroll
      for (int nf = 0; nf < 4; ++nf) {
        acc[m][nf] = __builtin_amdgcn_mfma_f32_16x16x32_f16(ah, b[nf], acc[m][nf], 0, 0, 0);
        acc[m][nf] = __builtin_amdgcn_mfma_f32_16x16x32_f16(ar, b[nf], acc[m][nf], 0, 0, 0);
      }
    }
  }

  #pragma unroll
  for (int m = 0; m < 8; ++m) {
    int x0 = m * 16 + (lane >> 4) * 4;
    #pragma unroll
    for (int nf = 0; nf < 4; ++nf) {
      int n = n0 + wave * 64 + nf * 16 + (lane & 15);
      #pragma unroll
      for (int r = 0; r < 4; ++r)
        att[(size_t)(x0 + r) * BH + n] = (_Float16)acc[m][nf][r];
    }
  }
}

// --------------------------- final linear -----------------------------------
// out[32768,1024] = att @ linW^T + linb.  128x128 tile, BK=64, dbuf LDS.
// bid remap: XCD = bid&7 owns m-tiles [32*xcd, 32*xcd+32); n = (bid>>3)&7.
__global__ __launch_bounds__(256) void k_final(const _Float16* __restrict__ att,
                                               const _Float16* __restrict__ Wl,
                                               const float* __restrict__ bvec,
                                               float* __restrict__ out) {
  __shared__ char smem[65536];
  const int tid = threadIdx.x, wave = tid >> 6, lane = tid & 63;
  const int j = blockIdx.x >> 3;
  const int m0 = (((blockIdx.x & 7) << 5) | (j >> 3)) * 128;
  const int n0 = (j & 7) * 128;
  const int mh = (wave & 1) * 64, nh = (wave >> 1) * 64;

  f32x4 acc[4][4];
  #pragma unroll
  for (int i = 0; i < 4; ++i)
    #pragma unroll
    for (int jj = 0; jj < 4; ++jj) acc[i][jj] = (f32x4){0.f, 0.f, 0.f, 0.f};

  auto stage = [&](int p, int k0) {
    char* base = smem + p * 32768;
    #pragma unroll
    for (int q = 0; q < 8; ++q) {
      int grp = q * 4 + wave;
      char* dst = base + grp * 1024;
      int s = grp * 64 + lane;
      if (s < 1024) {
        int r = s >> 3, c = s & 7;
        int kc = c ^ (r & 7);
        g2l16(dst, att + (size_t)(m0 + r) * 1024 + k0 + kc * 8);
      } else {
        int sb = s - 1024;
        int r = sb >> 3, c = sb & 7;
        int kc = c ^ (r & 7);
        g2l16(dst, Wl + (size_t)(n0 + r) * 1024 + k0 + kc * 8);
      }
    }
  };

  stage(0, 0);
  for (int iter = 0; iter < 16; ++iter) {
    int p = iter & 1;
    __syncthreads();
    if (iter + 1 < 16) stage(1 - p, (iter + 1) * 64);
    const char* At = smem + p * 32768;
    const char* Bt = At + 16384;
    #pragma unroll
    for (int k32 = 0; k32 < 2; ++k32) {
      int kc = k32 * 4 + (lane >> 4);
      half8 a[4], b[4];
      #pragma unroll
      for (int i = 0; i < 4; ++i) {
        int ra = mh + i * 16 + (lane & 15);
        a[i] = *(const half8*)(At + ra * 128 + ((kc ^ (ra & 7)) * 16));
        int rb = nh + i * 16 + (lane & 15);
        b[i] = *(const half8*)(Bt + rb * 128 + ((kc ^ (rb & 7)) * 16));
      }
      #pragma unroll
      for (int i = 0; i < 4; ++i)
        #pragma unroll
        for (int jj = 0; jj < 4; ++jj)
          acc[i][jj] = __builtin_amdgcn_mfma_f32_16x16x32_f16(a[i], b[jj], acc[i][jj], 0, 0, 0);
    }
  }

  #pragma unroll
  for (int i = 0; i < 4; ++i) {
    int m = m0 + mh + i * 16 + (lane >> 4) * 4;
    #pragma unroll
    for (int jj = 0; jj < 4; ++jj) {
      int n = n0 + nh + jj * 16 + (lane & 15);
      float bv = bvec[n];
      #pragma unroll
      for (int r = 0; r < 4; ++r)
        out[(size_t)(m + r) * 1024 + n] = acc[i][jj][r] + bv;
    }
  }
}

// --------------------------- launch -----------------------------------------
extern "C" void kernel_launch(void* const* d_in, const int* in_sizes, int n_in,
                              void* d_out, int out_size, void* d_ws, size_t ws_size,
                              hipStream_t stream) {
  const float* X     = (const float*)d_in[0];
  const float* h0    = (const float*)d_in[1];
  const float* c0    = (const float*)d_in[2];
  const float* Wih   = (const float*)d_in[3];
  const float* Whh   = (const float*)d_in[4];
  const float* bih   = (const float*)d_in[5];
  const float* bhh   = (const float*)d_in[6];
  const float* attnW = (const float*)d_in[7];
  const float* linW  = (const float*)d_in[8];
  const float* linb  = (const float*)d_in[9];
  float* out = (float*)d_out;
  char* ws = (char*)d_ws;

  // workspace layout (bytes), ~212 MB total
  _Float16* Xh  = (_Float16*)(ws + 0);           // 67,108,864
  _Float16* Wc  = (_Float16*)(ws + 67108864);    // 16,777,216
  _Float16* Wl  = (_Float16*)(ws + 83886080);    //  2,097,152
  _Float16* hs  = (_Float16*)(ws + 85983232);    // 129 slots * 524,288
  _Float16* att = (_Float16*)(ws + 153616384);   // 67,108,864
  float* cbuf   = (float*)(ws + 220725248);      //  1,048,576
  float* bias   = (float*)(ws + 221773824);      //     16,384
  _Float16* Ahm = (_Float16*)(ws + 221790208);   //     32,768
  _Float16* Arm = (_Float16*)(ws + 221822976);   //     32,768

  k_cvt<<<16384, 256, 0, stream>>>(X, Xh);
  k_wcat<<<4096, 256, 0, stream>>>(Wih, Whh, Wc);
  k_cvt<<<512, 256, 0, stream>>>(linW, Wl);
  k_init<<<1024, 256, 0, stream>>>(h0, c0, bih, bhh, hs, cbuf, bias);
  k_softmax<<<128, 64, 0, stream>>>(attnW, Ahm, Arm);

  for (int t = 0; t < S_; ++t)
    k_step<<<256, 512, 0, stream>>>(Xh, Wc, bias, hs, cbuf, t);

  k_attn<<<1024, 256, 0, stream>>>(Ahm, Arm, hs, att);
  k_final<<<2048, 256, 0, stream>>>(att, Wl, linb, out);
}